// Round 4
// baseline (113.193 us; speedup 1.0000x reference)
//
#include <hip/hip_runtime.h>
#include <hip/hip_bf16.h>

typedef __attribute__((ext_vector_type(8))) short bf16x8;
typedef __attribute__((ext_vector_type(4))) float f32x4;
typedef __attribute__((ext_vector_type(8))) unsigned short u16x8;
typedef __attribute__((ext_vector_type(4))) unsigned short u16x4;

__device__ __forceinline__ unsigned short f2bf_rtne(float f) {
    unsigned int u = __float_as_uint(f);
    u += 0x7FFFu + ((u >> 16) & 1u);
    return (unsigned short)(u >> 16);
}

__device__ __forceinline__ void gl2lds16(const void* g, void* l) {
    __builtin_amdgcn_global_load_lds((const __attribute__((address_space(1))) void*)g,
                                     (__attribute__((address_space(3))) void*)l, 16, 0, 0);
}

// ---------------- prep: weight -> {w_bf16, hash_weight_bf16} (x/x_hash conversion now fused in GEMM) ----------------
#define NB 16
__global__ void hash_prep(const float* __restrict__ w,
                          const float* __restrict__ a0, const float* __restrict__ a1,
                          const float* __restrict__ a2, const float* __restrict__ vals,
                          unsigned short* __restrict__ wbf, unsigned short* __restrict__ hwbf) {
    float A0[NB], A1[NB], A2[NB], V[NB];
#pragma unroll
    for (int b = 0; b < NB; ++b) {
        A0[b] = a0[b] * 100.0f;
        A1[b] = a1[b] * 100.0f;
        A2[b] = a2[b] * 100.0f;
        V[b]  = vals[b];
    }
    const int n4 = (2048 * 2048) / 4;
    const int stride = gridDim.x * blockDim.x;
    for (int i = blockIdx.x * blockDim.x + threadIdx.x; i < n4; i += stride) {
        float4 wv = ((const float4*)w)[i];
        float win[4] = {wv.x, wv.y, wv.z, wv.w};
        u16x4 wr, hr;
#pragma unroll
        for (int c = 0; c < 4; ++c) {
            float xx = win[c];
            float x2 = xx * xx;
            float l[NB];
            float mx = -1e30f;
#pragma unroll
            for (int b = 0; b < NB; ++b) {
                l[b] = fmaf(A1[b], xx, fmaf(A2[b], x2, A0[b]));
                mx = fmaxf(mx, l[b]);
            }
            float s = 0.0f, acc = 0.0f;
#pragma unroll
            for (int b = 0; b < NB; ++b) {
                float e = __expf(l[b] - mx);
                s += e;
                acc = fmaf(e, V[b], acc);
            }
            wr[c] = f2bf_rtne(xx);
            hr[c] = f2bf_rtne(acc / s);
        }
        *((u16x4*)wbf + i)  = wr;
        *((u16x4*)hwbf + i) = hr;
    }
}

// ---------------- 256x256-tile 8-phase bf16 GEMM with fused f32->bf16 A-conversion ----------------
// A (x / x_hash) read as f32, reg-staged (T14): float4 x4 load -> cvt -> swizzled ds_write_b128.
// B (w / hash_w bf16) via global_load_lds with pre-swizzled source (rule 21). BK=64, 8 waves.
// vmcnt discipline: compiler's mandatory waits on the A float4 regs (youngest in queue) drain
// all older B-DMAs (in-order vmcnt) exactly before each buffer's first read; asm gates only in
// prologue/tail. Memory-clobber asm per phase pins issue order.
__global__ __launch_bounds__(512, 2) void gemm256(
    const float* __restrict__ Axf, const float* __restrict__ Ahf,
    const unsigned short* __restrict__ Bw, const unsigned short* __restrict__ Bh,
    const float* __restrict__ bias,
    float* __restrict__ Cx, float* __restrict__ Chh) {
    const int K = 2048, N = 2048;

    __shared__ unsigned short lds[65536];  // A: [2][16384], B at +32768: [2][16384]

    // T1: XCD-aware remap of the 3D grid (16 x, 8 y, 2 z -> 256 linear)
    const int lin  = blockIdx.x + (blockIdx.y << 4) + (blockIdx.z << 7);
    const int swz  = (lin & 7) * 32 + (lin >> 3);
    const int brow = swz & 15;
    const int bcol = (swz >> 4) & 7;
    const int zz   = swz >> 7;

    const float* Af = zz ? Ahf : Axf;
    const unsigned short* Bm = zz ? Bh : Bw;
    float* C = zz ? Chh : Cx;

    const int tid  = threadIdx.x;
    const int lane = tid & 63;
    const int wid  = tid >> 6;
    const int wr = wid >> 2;          // 0..1 : wave row (128 rows)
    const int wc = wid & 3;           // 0..3 : wave col (64 cols)
    const int fr = lane & 15;
    const int fq = lane >> 4;         // 0..3

    // A staging (f32, linear global read; swizzle applied at ds_write)
    const int srow = tid >> 3;                               // 0..63
    const float* gAf = Af + (size_t)(brow * 256 + srow) * K + (tid & 7) * 8;
    const int aswz = ((tid & 7) ^ (srow & 7)) * 8;           // swizzled granule slot (ushorts)

    // B staging source (pre-swizzled granule, bf16 DMA)
    const int sg8 = ((tid & 7) ^ (srow & 7)) * 8;
    const unsigned short* gB = Bm + (size_t)(bcol * 256 + srow) * K + sg8;
    const int wbase = wid * 512;                             // wave-uniform LDS base (ushorts)

    // ds_read swizzled granule offsets (ushorts): granule (kk*4+fq) ^ (fr&7)
    const int g0 = (fq ^ (fr & 7)) * 8;   // kk=0
    const int g1 = g0 ^ 32;               // kk=1

#define LOAD_A(R, h, j) {                                                       \
    const float* _p = gAf + (size_t)(h) * 128 * K + (j) * 64;                   \
    R[0] = *(const float4*)(_p);                                                \
    R[1] = *(const float4*)(_p + 4);                                            \
    R[2] = *(const float4*)(_p + (size_t)64 * K);                               \
    R[3] = *(const float4*)(_p + (size_t)64 * K + 4); }

#define WRITE_A(R, buf, h) {                                                    \
    unsigned short* _d = lds + (buf) * 16384 + (h) * 8192 + srow * 64 + aswz;   \
    u16x8 _v0, _v1;                                                             \
    _v0[0] = f2bf_rtne(R[0].x); _v0[1] = f2bf_rtne(R[0].y);                     \
    _v0[2] = f2bf_rtne(R[0].z); _v0[3] = f2bf_rtne(R[0].w);                     \
    _v0[4] = f2bf_rtne(R[1].x); _v0[5] = f2bf_rtne(R[1].y);                     \
    _v0[6] = f2bf_rtne(R[1].z); _v0[7] = f2bf_rtne(R[1].w);                     \
    _v1[0] = f2bf_rtne(R[2].x); _v1[1] = f2bf_rtne(R[2].y);                     \
    _v1[2] = f2bf_rtne(R[2].z); _v1[3] = f2bf_rtne(R[2].w);                     \
    _v1[4] = f2bf_rtne(R[3].x); _v1[5] = f2bf_rtne(R[3].y);                     \
    _v1[6] = f2bf_rtne(R[3].z); _v1[7] = f2bf_rtne(R[3].w);                     \
    *(u16x8*)_d = _v0;                                                          \
    *(u16x8*)(_d + 4096) = _v1; }

#define STAGE_B(buf, h, j) {                                                    \
    const unsigned short* _g = gB + (size_t)((h) * 128) * K + (j) * 64;         \
    gl2lds16(_g,                  lds + 32768 + (buf) * 16384 + (h) * 8192 + wbase); \
    gl2lds16(_g + (size_t)64 * K, lds + 32768 + (buf) * 16384 + (h) * 8192 + 4096 + wbase); }

#define LDA(dst, buf, mblk) {                                                   \
    const unsigned short* _p = lds + (buf) * 16384 + (wr * 128 + (mblk) * 16 + fr) * 64; \
    dst[0] = *(const bf16x8*)(_p + g0);                                         \
    dst[1] = *(const bf16x8*)(_p + g1); }
#define LDB(dst, buf, nblk) {                                                   \
    const unsigned short* _p = lds + 32768 + (buf) * 16384 + (wc * 64 + (nblk) * 16 + fr) * 64; \
    dst[0] = *(const bf16x8*)(_p + g0);                                         \
    dst[1] = *(const bf16x8*)(_p + g1); }

#define MM(mi, n, kk, AF) acc[mi][n] = __builtin_amdgcn_mfma_f32_16x16x32_bf16(AF[kk], bfr[n][kk], acc[mi][n], 0, 0, 0)

#define PHASE(q, buf, STG, GATE) {                                              \
    if ((q) == 0) {                                                             \
        LDB(bfr[0], buf, 0); LDB(bfr[1], buf, 1);                               \
        LDB(bfr[2], buf, 2); LDB(bfr[3], buf, 3);                               \
    }                                                                           \
    LDA(af0, buf, 2 * (q)); LDA(af1, buf, 2 * (q) + 1);                         \
    STG;                                                                        \
    __builtin_amdgcn_s_barrier();                                               \
    asm volatile("s_waitcnt lgkmcnt(0)" ::: "memory");                          \
    __builtin_amdgcn_s_setprio(1);                                              \
    MM(2*(q),0,0,af0); MM(2*(q)+1,0,0,af1); MM(2*(q),1,0,af0); MM(2*(q)+1,1,0,af1); \
    MM(2*(q),2,0,af0); MM(2*(q)+1,2,0,af1); MM(2*(q),3,0,af0); MM(2*(q)+1,3,0,af1); \
    MM(2*(q),0,1,af0); MM(2*(q)+1,0,1,af1); MM(2*(q),1,1,af0); MM(2*(q)+1,1,1,af1); \
    MM(2*(q),2,1,af0); MM(2*(q)+1,2,1,af1); MM(2*(q),3,1,af0); MM(2*(q)+1,3,1,af1); \
    __builtin_amdgcn_s_setprio(0);                                              \
    GATE;                                                                       \
    __builtin_amdgcn_s_barrier(); }

    float4 aP[4], aQ[4];

    // prologue: A(0) reg-staged (both halves), B(0)/B(1) DMA, then A(1)h0 loads in flight.
    LOAD_A(aP, 0, 0);
    LOAD_A(aQ, 1, 0);
    STAGE_B(0, 0, 0); STAGE_B(0, 1, 0);
    STAGE_B(1, 0, 1); STAGE_B(1, 1, 1);
    WRITE_A(aP, 0, 0);                 // compiler vmcnt wait: leaves aQ + all B in flight
    WRITE_A(aQ, 0, 1);                 // leaves B(0),B(1) in flight
    LOAD_A(aP, 0, 1);                  // tile1 h0
    asm volatile("s_waitcnt vmcnt(8)" ::: "memory");   // B(0) landed; B(1)+aP stay in flight
    asm volatile("s_waitcnt lgkmcnt(0)" ::: "memory"); // A(0) ds_writes visible
    __builtin_amdgcn_s_barrier();

    f32x4 acc[8][4] = {};
    bf16x8 bfr[4][2], af0[2], af1[2];

    // steady state: phases 1-4 = tile 2t (buf0), 5-8 = tile 2t+1 (buf1)
    // A: P1 write(2t+1,h0)+load h1; P2 write h1; P4 load(2t+2,h0); P5 write h0 + load h1; P6 write h1; P8 load(2t+3,h0)
    // B: P3/P4 DMA (2t+2)->buf0; P7/P8 DMA (2t+3)->buf1
#pragma unroll 1
    for (int t = 0; t < 15; ++t) {
        const int j1 = 2 * t + 1, j2 = 2 * t + 2, j3 = 2 * t + 3;
        PHASE(0, 0, { WRITE_A(aP, 1, 0); LOAD_A(aQ, 1, j1); }, );
        PHASE(1, 0, { WRITE_A(aQ, 1, 1); }, );
        PHASE(2, 0, { STAGE_B(0, 0, j2); }, );
        PHASE(3, 0, { LOAD_A(aP, 0, j2); STAGE_B(0, 1, j2); }, );
        PHASE(0, 1, { WRITE_A(aP, 0, 0); LOAD_A(aQ, 1, j2); }, );
        PHASE(1, 1, { WRITE_A(aQ, 0, 1); }, );
        PHASE(2, 1, { STAGE_B(1, 0, j3); }, );
        PHASE(3, 1, { LOAD_A(aP, 0, j3); STAGE_B(1, 1, j3); }, );
    }
    // tail: tiles 30 (buf0), 31 (buf1); A(31) written here, B(31) DMA'd at t=14
    PHASE(0, 0, { WRITE_A(aP, 1, 0); LOAD_A(aQ, 1, 31); }, );
    PHASE(1, 0, { WRITE_A(aQ, 1, 1); }, );
    PHASE(2, 0, , );
    PHASE(3, 0, , asm volatile("s_waitcnt vmcnt(0)" ::: "memory"));
    PHASE(0, 1, , );
    PHASE(1, 1, , );
    PHASE(2, 1, , );
    PHASE(3, 1, , );

    // epilogue: C[row][col] = acc + bias; row = m*16 + fq*4 + r, col = n*16 + fr (verified mapping)
#pragma unroll
    for (int n = 0; n < 4; ++n) {
        const int col = bcol * 256 + wc * 64 + n * 16 + fr;
        const float bv = bias[col];
#pragma unroll
        for (int m = 0; m < 8; ++m) {
            const int row0 = brow * 256 + wr * 128 + m * 16 + fq * 4;
#pragma unroll
            for (int r = 0; r < 4; ++r)
                C[(size_t)(row0 + r) * N + col] = acc[m][n][r] + bv;
        }
    }
#undef LOAD_A
#undef WRITE_A
#undef STAGE_B
#undef LDA
#undef LDB
#undef MM
#undef PHASE
}

extern "C" void kernel_launch(void* const* d_in, const int* in_sizes, int n_in,
                              void* d_out, int out_size, void* d_ws, size_t ws_size,
                              hipStream_t stream) {
    const float* x    = (const float*)d_in[0];
    const float* xh   = (const float*)d_in[1];
    const float* w    = (const float*)d_in[2];
    const float* bias = (const float*)d_in[3];
    const float* a0   = (const float*)d_in[4];
    const float* a1   = (const float*)d_in[5];
    const float* a2   = (const float*)d_in[6];
    const float* vals = (const float*)d_in[7];

    float* out  = (float*)d_out;
    float* outh = out + (size_t)4096 * 2048;

    char* ws = (char*)d_ws;
    unsigned short* wb  = (unsigned short*)(ws);                             // 8 MB
    unsigned short* hwb = (unsigned short*)(ws + (size_t)8 * 1024 * 1024);   // 8 MB

    hash_prep<<<1024, 256, 0, stream>>>(w, a0, a1, a2, vals, wb, hwb);

    dim3 grid(4096 / 256, 2048 / 256, 2);
    gemm256<<<grid, 512, 0, stream>>>(x, xh, wb, hwb, bias, out, outh);
}

// Round 6
// 108.161 us; speedup vs baseline: 1.0465x; 1.0465x over previous
//
#include <hip/hip_runtime.h>
#include <hip/hip_bf16.h>

typedef __attribute__((ext_vector_type(8))) short bf16x8;
typedef __attribute__((ext_vector_type(16))) float f32x16;
typedef __attribute__((ext_vector_type(8))) unsigned short u16x8;
typedef __attribute__((ext_vector_type(4))) unsigned short u16x4;

__device__ __forceinline__ unsigned short f2bf_rtne(float f) {
    unsigned int u = __float_as_uint(f);
    u += 0x7FFFu + ((u >> 16) & 1u);
    return (unsigned short)(u >> 16);
}

__device__ __forceinline__ void gl2lds16(const void* g, void* l) {
    __builtin_amdgcn_global_load_lds((const __attribute__((address_space(1))) void*)g,
                                     (__attribute__((address_space(3))) void*)l, 16, 0, 0);
}

// ---------------- fused prep: job0/1 = f32->bf16 convert (x, x_hash); job2 = hash_weight ----------------
#define NB 16
__global__ void prep_all(const float* __restrict__ x, const float* __restrict__ xh,
                         const float* __restrict__ w,
                         const float* __restrict__ a0, const float* __restrict__ a1,
                         const float* __restrict__ a2, const float* __restrict__ vals,
                         unsigned short* __restrict__ xb, unsigned short* __restrict__ xhb,
                         unsigned short* __restrict__ wbf, unsigned short* __restrict__ hwbf) {
    const int job = blockIdx.y;
    const int stride = gridDim.x * blockDim.x;
    int i = blockIdx.x * blockDim.x + threadIdx.x;
    if (job < 2) {
        const float* in = job ? xh : x;
        unsigned short* out = job ? xhb : xb;
        const int n8 = (4096 * 2048) / 8;
        for (; i < n8; i += stride) {
            const float4* p = (const float4*)in + (size_t)i * 2;
            float4 v0 = p[0];
            float4 v1 = p[1];
            u16x8 r;
            r[0] = f2bf_rtne(v0.x); r[1] = f2bf_rtne(v0.y); r[2] = f2bf_rtne(v0.z); r[3] = f2bf_rtne(v0.w);
            r[4] = f2bf_rtne(v1.x); r[5] = f2bf_rtne(v1.y); r[6] = f2bf_rtne(v1.z); r[7] = f2bf_rtne(v1.w);
            *((u16x8*)out + i) = r;
        }
    } else {
        float A0[NB], A1[NB], A2[NB], V[NB];
#pragma unroll
        for (int b = 0; b < NB; ++b) {
            A0[b] = a0[b] * 100.0f;
            A1[b] = a1[b] * 100.0f;
            A2[b] = a2[b] * 100.0f;
            V[b]  = vals[b];
        }
        const int n4 = (2048 * 2048) / 4;
        for (; i < n4; i += stride) {
            float4 wv = ((const float4*)w)[i];
            float win[4] = {wv.x, wv.y, wv.z, wv.w};
            u16x4 wr, hr;
#pragma unroll
            for (int c = 0; c < 4; ++c) {
                float xx = win[c];
                float x2 = xx * xx;
                float l[NB];
                float mx = -1e30f;
#pragma unroll
                for (int b = 0; b < NB; ++b) {
                    l[b] = fmaf(A1[b], xx, fmaf(A2[b], x2, A0[b]));
                    mx = fmaxf(mx, l[b]);
                }
                float s = 0.0f, acc = 0.0f;
#pragma unroll
                for (int b = 0; b < NB; ++b) {
                    float e = __expf(l[b] - mx);
                    s += e;
                    acc = fmaf(e, V[b], acc);
                }
                wr[c] = f2bf_rtne(xx);
                hr[c] = f2bf_rtne(acc / s);
            }
            *((u16x4*)wbf + i)  = wr;
            *((u16x4*)hwbf + i) = hr;
        }
    }
}

// ---------------- 256x256-tile 8-phase bf16 GEMM (32x32x16 MFMA), C = A * B^T + bias ----------------
// BM=BN=256, BK=64, 8 waves (2Mx4N), 128KB LDS double-buffer, K=N=2048, M=4096.
// T2 (rule 21): linear LDS dest for global_load_lds; global source granule pre-XOR'd with
// (row&7); ds_read applies the same XOR.
// RACE DISCIPLINE (round-5 lesson): every STAGE into a region is >=2 barriers after that
// region's LAST read. Therefore ALL B reads are confined to P0 of each buffer's pass
// (bq[2][4] live across phases); A is read per-phase. Staging slots = round-2's proven set.
// Counted vmcnt(4) gates only at phases 4/8.
__global__ __launch_bounds__(512, 2) void gemm256(
    const unsigned short* __restrict__ Ax, const unsigned short* __restrict__ Ah,
    const unsigned short* __restrict__ Bw, const unsigned short* __restrict__ Bh,
    const float* __restrict__ bias,
    float* __restrict__ Cx, float* __restrict__ Chh) {
    const int K = 2048, N = 2048;

    __shared__ unsigned short lds[65536];  // A: [2][16384], B at +32768: [2][16384]

    const unsigned short* A  = blockIdx.z ? Ah : Ax;
    const unsigned short* Bm = blockIdx.z ? Bh : Bw;
    float* C = blockIdx.z ? Chh : Cx;

    const int tid  = threadIdx.x;
    const int lane = tid & 63;
    const int wid  = tid >> 6;
    const int wr = wid >> 2;          // 0..1 : wave row (128 rows)
    const int wc = wid & 3;           // 0..3 : wave col (64 cols)
    const int l31 = lane & 31;
    const int kh  = lane >> 5;        // k-half within fragment
    const int brow = blockIdx.x;
    const int bcol = blockIdx.y;

    // staging source (pre-swizzled granule): thread t covers row (t>>3), physical granule (t&7)
    const int srow = tid >> 3;                              // 0..63
    const int sg8  = ((tid & 7) ^ (srow & 7)) * 8;          // logical k-offset (elements)
    const unsigned short* gA = A  + (size_t)(brow * 256 + srow) * K + sg8;
    const unsigned short* gB = Bm + (size_t)(bcol * 256 + srow) * K + sg8;
    const int wbase = wid * 512;                            // wave-uniform LDS base (ushorts)

    // ds_read swizzled granule offsets (ushorts) per k-phase q: granule (2q+kh) ^ (lane&7)
    const int ax = lane & 7;
    const int gq[4] = { ((0 + kh) ^ ax) * 8, ((2 + kh) ^ ax) * 8,
                        ((4 + kh) ^ ax) * 8, ((6 + kh) ^ ax) * 8 };
    const int aBase = (wr * 128 + l31) * 64;            // + m*2048 per m-block
    const int bBase = 32768 + (wc * 64 + l31) * 64;     // + n*2048 per n-block

#define STAGE_A(buf, h, j) {                                                    \
    const unsigned short* _g = gA + (size_t)((h) * 128) * K + (j) * 64;         \
    gl2lds16(_g,                  lds + (buf) * 16384 + (h) * 8192 + wbase);    \
    gl2lds16(_g + (size_t)64 * K, lds + (buf) * 16384 + (h) * 8192 + 4096 + wbase); }
#define STAGE_B(buf, h, j) {                                                    \
    const unsigned short* _g = gB + (size_t)((h) * 128) * K + (j) * 64;         \
    gl2lds16(_g,                  lds + 32768 + (buf) * 16384 + (h) * 8192 + wbase); \
    gl2lds16(_g + (size_t)64 * K, lds + 32768 + (buf) * 16384 + (h) * 8192 + 4096 + wbase); }

#define MM(m, n, q) acc[m][n] = __builtin_amdgcn_mfma_f32_32x32x16_bf16(af[m], bq[n][q], acc[m][n], 0, 0, 0)

#define PHASE(q, buf, STG, GATE) {                                              \
    if ((q) == 0) {   /* all B-frags for this buffer's pass */                  \
        const unsigned short* _pb = lds + (buf) * 16384 + bBase;                \
        bq[0][0] = *(const bf16x8*)(_pb + gq[0]);                               \
        bq[0][1] = *(const bf16x8*)(_pb + gq[1]);                               \
        bq[0][2] = *(const bf16x8*)(_pb + gq[2]);                               \
        bq[0][3] = *(const bf16x8*)(_pb + gq[3]);                               \
        bq[1][0] = *(const bf16x8*)(_pb + 2048 + gq[0]);                        \
        bq[1][1] = *(const bf16x8*)(_pb + 2048 + gq[1]);                        \
        bq[1][2] = *(const bf16x8*)(_pb + 2048 + gq[2]);                        \
        bq[1][3] = *(const bf16x8*)(_pb + 2048 + gq[3]);                        \
    }                                                                           \
    {                                                                           \
        const unsigned short* _pa = lds + (buf) * 16384 + aBase + gq[q];        \
        af[0] = *(const bf16x8*)(_pa);                                          \
        af[1] = *(const bf16x8*)(_pa + 2048);                                   \
        af[2] = *(const bf16x8*)(_pa + 4096);                                   \
        af[3] = *(const bf16x8*)(_pa + 6144);                                   \
    }                                                                           \
    STG;                                                                        \
    __builtin_amdgcn_s_barrier();                                               \
    asm volatile("s_waitcnt lgkmcnt(0)" ::: "memory");                          \
    __builtin_amdgcn_s_setprio(1);                                              \
    MM(0, 0, q); MM(1, 0, q); MM(2, 0, q); MM(3, 0, q);                         \
    MM(0, 1, q); MM(1, 1, q); MM(2, 1, q); MM(3, 1, q);                         \
    __builtin_amdgcn_s_setprio(0);                                              \
    GATE;                                                                       \
    __builtin_amdgcn_s_barrier(); }

    // prologue: A(0), B(0), B(1) = 12 loads/thread; vmcnt(4) leaves exactly B(1) in flight
    STAGE_A(0, 0, 0); STAGE_A(0, 1, 0);
    STAGE_B(0, 0, 0); STAGE_B(0, 1, 0);
    STAGE_B(1, 0, 1); STAGE_B(1, 1, 1);
    asm volatile("s_waitcnt vmcnt(4)" ::: "memory");
    __builtin_amdgcn_s_barrier();

    f32x16 acc[4][2] = {};
    bf16x8 af[4], bq[2][4];

    // steady state: tiles 2t (buf0, phases 1-4) and 2t+1 (buf1, phases 5-8)
    // stage slots (each >=2 barriers after its region's last read):
    //   P1:A(2t+1)h0->buf1  P2:A h1->buf1  P3:B(2t+2)h0->buf0  P4:B h1->buf0 + vmcnt(4)
    //   P5:A(2t+2)h0->buf0  P6:A h1->buf0  P7:B(2t+3)h0->buf1  P8:B h1->buf1 + vmcnt(4)
#pragma unroll 1
    for (int t = 0; t < 15; ++t) {
        const int j1 = 2 * t + 1, j2 = 2 * t + 2, j3 = 2 * t + 3;
        PHASE(0, 0, STAGE_A(1, 0, j1), );
        PHASE(1, 0, STAGE_A(1, 1, j1), );
        PHASE(2, 0, STAGE_B(0, 0, j2), );
        PHASE(3, 0, STAGE_B(0, 1, j2), asm volatile("s_waitcnt vmcnt(4)" ::: "memory"));
        PHASE(0, 1, STAGE_A(0, 0, j2), );
        PHASE(1, 1, STAGE_A(0, 1, j2), );
        PHASE(2, 1, STAGE_B(1, 0, j3), );
        PHASE(3, 1, STAGE_B(1, 1, j3), asm volatile("s_waitcnt vmcnt(4)" ::: "memory"));
    }
    // tail: tiles 30 (buf0), 31 (buf1); A(31) staged here, B(31) staged at t=14
    PHASE(0, 0, STAGE_A(1, 0, 31), );
    PHASE(1, 0, STAGE_A(1, 1, 31), );
    PHASE(2, 0, , );
    PHASE(3, 0, , asm volatile("s_waitcnt vmcnt(0)" ::: "memory"));
    PHASE(0, 1, , );
    PHASE(1, 1, , );
    PHASE(2, 1, , );
    PHASE(3, 1, , );

    // epilogue: C[row][col] = acc + bias
    // 32x32 C/D mapping (m74/m101 verified): col = lane&31, row = (reg&3) + 8*(reg>>2) + 4*(lane>>5)
#pragma unroll
    for (int n = 0; n < 2; ++n) {
        const int col = bcol * 256 + wc * 64 + n * 32 + l31;
        const float bv = bias[col];
#pragma unroll
        for (int m = 0; m < 4; ++m) {
            const int row_base = brow * 256 + wr * 128 + m * 32 + 4 * kh;
#pragma unroll
            for (int r = 0; r < 16; ++r) {
                const int row = row_base + (r & 3) + 8 * (r >> 2);
                C[(size_t)row * N + col] = acc[m][n][r] + bv;
            }
        }
    }
#undef STAGE_A
#undef STAGE_B
#undef MM
#undef PHASE
}

extern "C" void kernel_launch(void* const* d_in, const int* in_sizes, int n_in,
                              void* d_out, int out_size, void* d_ws, size_t ws_size,
                              hipStream_t stream) {
    const float* x    = (const float*)d_in[0];
    const float* xh   = (const float*)d_in[1];
    const float* w    = (const float*)d_in[2];
    const float* bias = (const float*)d_in[3];
    const float* a0   = (const float*)d_in[4];
    const float* a1   = (const float*)d_in[5];
    const float* a2   = (const float*)d_in[6];
    const float* vals = (const float*)d_in[7];

    float* out  = (float*)d_out;
    float* outh = out + (size_t)4096 * 2048;

    char* ws = (char*)d_ws;
    unsigned short* xb  = (unsigned short*)(ws);                              // 16 MB
    unsigned short* xhb = (unsigned short*)(ws + (size_t)16 * 1024 * 1024);   // 16 MB
    unsigned short* wb  = (unsigned short*)(ws + (size_t)32 * 1024 * 1024);   //  8 MB
    unsigned short* hwb = (unsigned short*)(ws + (size_t)40 * 1024 * 1024);   //  8 MB

    prep_all<<<dim3(2048, 3), 256, 0, stream>>>(x, xh, w, a0, a1, a2, vals, xb, xhb, wb, hwb);

    dim3 grid(4096 / 256, 2048 / 256, 2);
    gemm256<<<grid, 512, 0, stream>>>(xb, xhb, wb, hwb, bias, out, outh);
}

// Round 7
// 98.810 us; speedup vs baseline: 1.1456x; 1.0946x over previous
//
#include <hip/hip_runtime.h>
#include <hip/hip_bf16.h>

typedef __attribute__((ext_vector_type(8))) short bf16x8;
typedef __attribute__((ext_vector_type(4))) float f32x4;
typedef __attribute__((ext_vector_type(8))) unsigned short u16x8;
typedef __attribute__((ext_vector_type(4))) unsigned short u16x4;

__device__ __forceinline__ unsigned short f2bf_rtne(float f) {
    unsigned int u = __float_as_uint(f);
    u += 0x7FFFu + ((u >> 16) & 1u);
    return (unsigned short)(u >> 16);
}

__device__ __forceinline__ void gl2lds16(const void* g, void* l) {
    __builtin_amdgcn_global_load_lds((const __attribute__((address_space(1))) void*)g,
                                     (__attribute__((address_space(3))) void*)l, 16, 0, 0);
}

// ---------------- fused prep: job0/1 = f32->bf16 convert (x, x_hash); job2 = hash_weight ----------------
#define NB 16
__global__ void prep_all(const float* __restrict__ x, const float* __restrict__ xh,
                         const float* __restrict__ w,
                         const float* __restrict__ a0, const float* __restrict__ a1,
                         const float* __restrict__ a2, const float* __restrict__ vals,
                         unsigned short* __restrict__ xb, unsigned short* __restrict__ xhb,
                         unsigned short* __restrict__ wbf, unsigned short* __restrict__ hwbf) {
    const int job = blockIdx.y;
    const int stride = gridDim.x * blockDim.x;
    int i = blockIdx.x * blockDim.x + threadIdx.x;
    if (job < 2) {
        const float* in = job ? xh : x;
        unsigned short* out = job ? xhb : xb;
        const int n8 = (4096 * 2048) / 8;
        for (; i < n8; i += stride) {
            const float4* p = (const float4*)in + (size_t)i * 2;
            float4 v0 = p[0];
            float4 v1 = p[1];
            u16x8 r;
            r[0] = f2bf_rtne(v0.x); r[1] = f2bf_rtne(v0.y); r[2] = f2bf_rtne(v0.z); r[3] = f2bf_rtne(v0.w);
            r[4] = f2bf_rtne(v1.x); r[5] = f2bf_rtne(v1.y); r[6] = f2bf_rtne(v1.z); r[7] = f2bf_rtne(v1.w);
            *((u16x8*)out + i) = r;
        }
    } else {
        float A0[NB], A1[NB], A2[NB], V[NB];
#pragma unroll
        for (int b = 0; b < NB; ++b) {
            A0[b] = a0[b] * 100.0f;
            A1[b] = a1[b] * 100.0f;
            A2[b] = a2[b] * 100.0f;
            V[b]  = vals[b];
        }
        const int n4 = (2048 * 2048) / 4;
        for (; i < n4; i += stride) {
            float4 wv = ((const float4*)w)[i];
            float win[4] = {wv.x, wv.y, wv.z, wv.w};
            u16x4 wr, hr;
#pragma unroll
            for (int c = 0; c < 4; ++c) {
                float xx = win[c];
                float x2 = xx * xx;
                float l[NB];
                float mx = -1e30f;
#pragma unroll
                for (int b = 0; b < NB; ++b) {
                    l[b] = fmaf(A1[b], xx, fmaf(A2[b], x2, A0[b]));
                    mx = fmaxf(mx, l[b]);
                }
                float s = 0.0f, acc = 0.0f;
#pragma unroll
                for (int b = 0; b < NB; ++b) {
                    float e = __expf(l[b] - mx);
                    s += e;
                    acc = fmaf(e, V[b], acc);
                }
                wr[c] = f2bf_rtne(xx);
                hr[c] = f2bf_rtne(acc / s);
            }
            *((u16x4*)wbf + i)  = wr;
            *((u16x4*)hwbf + i) = hr;
        }
    }
}

// ---------------- 256x256-tile 8-phase bf16 GEMM (16x16x32), hoisted fragment reads ----------------
// Sync skeleton (stages, vmcnt gates, barriers) is EXACTLY the proven round-2 set.
// Change: all of a buffer's fragment reads issue at the START of its pass (burst+A01+A23 at
// P1/P5; A45 at P2/P6; A67 at P3/P7) into ping-pong reg sets; the compiler's counted lgkm
// waits let each phase's MFMA start while later reads drain under the MFMA window.
// Visibility: buf0 DMAs drained by every wave at P8 gate+barrier; buf1 at P4 gate+barrier.
__global__ __launch_bounds__(512, 2) void gemm256(
    const unsigned short* __restrict__ Ax, const unsigned short* __restrict__ Ah,
    const unsigned short* __restrict__ Bw, const unsigned short* __restrict__ Bh,
    const float* __restrict__ bias,
    float* __restrict__ Cx, float* __restrict__ Chh) {
    const int K = 2048, N = 2048;

    __shared__ unsigned short lds[65536];  // A: [2][16384], B at +32768: [2][16384]

    const unsigned short* A  = blockIdx.z ? Ah : Ax;
    const unsigned short* Bm = blockIdx.z ? Bh : Bw;
    float* C = blockIdx.z ? Chh : Cx;

    const int tid  = threadIdx.x;
    const int lane = tid & 63;
    const int wid  = tid >> 6;
    const int wr = wid >> 2;          // 0..1 : wave row (128 rows)
    const int wc = wid & 3;           // 0..3 : wave col (64 cols)
    const int fr = lane & 15;
    const int fq = lane >> 4;         // 0..3
    const int brow = blockIdx.x;
    const int bcol = blockIdx.y;

    // staging source (pre-swizzled granule): thread t covers row (t>>3), physical granule (t&7)
    const int srow = tid >> 3;                              // 0..63
    const int sg8  = ((tid & 7) ^ (srow & 7)) * 8;          // logical k-offset (elements)
    const unsigned short* gA = A  + (size_t)(brow * 256 + srow) * K + sg8;
    const unsigned short* gB = Bm + (size_t)(bcol * 256 + srow) * K + sg8;
    const int wbase = wid * 512;                            // wave-uniform LDS base (ushorts)

    // ds_read swizzled granule offsets (round-2 pattern, measured 0-conflict)
    const int g0 = (fq ^ (fr & 7)) * 8;   // kk=0
    const int g1 = g0 ^ 32;               // kk=1

#define STAGE_A(buf, h, j) {                                                    \
    const unsigned short* _g = gA + (size_t)((h) * 128) * K + (j) * 64;         \
    gl2lds16(_g,                  lds + (buf) * 16384 + (h) * 8192 + wbase);    \
    gl2lds16(_g + (size_t)64 * K, lds + (buf) * 16384 + (h) * 8192 + 4096 + wbase); }
#define STAGE_B(buf, h, j) {                                                    \
    const unsigned short* _g = gB + (size_t)((h) * 128) * K + (j) * 64;         \
    gl2lds16(_g,                  lds + 32768 + (buf) * 16384 + (h) * 8192 + wbase); \
    gl2lds16(_g + (size_t)64 * K, lds + 32768 + (buf) * 16384 + (h) * 8192 + 4096 + wbase); }

#define RDA(dst, buf, mblk) {                                                   \
    const unsigned short* _p = lds + (buf) * 16384 + (wr * 128 + (mblk) * 16 + fr) * 64; \
    dst[0] = *(const bf16x8*)(_p + g0);                                         \
    dst[1] = *(const bf16x8*)(_p + g1); }
#define RDB(dst, buf, nblk) {                                                   \
    const unsigned short* _p = lds + 32768 + (buf) * 16384 + (wc * 64 + (nblk) * 16 + fr) * 64; \
    dst[0] = *(const bf16x8*)(_p + g0);                                         \
    dst[1] = *(const bf16x8*)(_p + g1); }
#define RD_BURST(buf) { RDB(bfr[0], buf, 0); RDB(bfr[1], buf, 1);               \
                        RDB(bfr[2], buf, 2); RDB(bfr[3], buf, 3); }

#define MM(mi, n, kk, AF) acc[mi][n] = __builtin_amdgcn_mfma_f32_16x16x32_bf16(AF[kk], bfr[n][kk], acc[mi][n], 0, 0, 0)

// phase body: bar -> (issue reads) -> (issue stage DMA) -> MFMA (compiler counted-lgkm) -> gate -> bar
#define PH(q, A0_, A1_, RDS, STG, GATE) {                                       \
    __builtin_amdgcn_s_barrier();                                               \
    asm volatile("" ::: "memory");                                              \
    RDS;                                                                        \
    STG;                                                                        \
    __builtin_amdgcn_s_setprio(1);                                              \
    MM(2*(q),0,0,A0_); MM(2*(q),0,1,A0_); MM(2*(q)+1,0,0,A1_); MM(2*(q)+1,0,1,A1_); \
    MM(2*(q),1,0,A0_); MM(2*(q),1,1,A0_); MM(2*(q)+1,1,0,A1_); MM(2*(q)+1,1,1,A1_); \
    MM(2*(q),2,0,A0_); MM(2*(q),2,1,A0_); MM(2*(q)+1,2,0,A1_); MM(2*(q)+1,2,1,A1_); \
    MM(2*(q),3,0,A0_); MM(2*(q),3,1,A0_); MM(2*(q)+1,3,0,A1_); MM(2*(q)+1,3,1,A1_); \
    __builtin_amdgcn_s_setprio(0);                                              \
    GATE;                                                                       \
    asm volatile("" ::: "memory");                                              \
    __builtin_amdgcn_s_barrier(); }

    // prologue: A(0), B(0) -> buf0; B(1) -> buf1 (12 loads); vmcnt(4) leaves B(1) in flight
    STAGE_A(0, 0, 0); STAGE_A(0, 1, 0);
    STAGE_B(0, 0, 0); STAGE_B(0, 1, 0);
    STAGE_B(1, 0, 1); STAGE_B(1, 1, 1);
    asm volatile("s_waitcnt vmcnt(4)" ::: "memory");
    __builtin_amdgcn_s_barrier();

    f32x4 acc[8][4] = {};
    bf16x8 bfr[4][2], aU0[2], aU1[2], aV0[2], aV1[2];

    // steady state: tiles 2t (buf0, P1-P4) and 2t+1 (buf1, P5-P8)
    // reads:  P1: burst(b0)+A01->U+A23->V   P2: A45->U   P3: A67->V   P4: -
    //         P5: burst(b1)+A01->U+A23->V   P6: A45->U   P7: A67->V   P8: -
    // stages: P1/P2: A(2t+1)->b1   P3/P4: B(2t+2)->b0 + gate vmcnt(4)
    //         P5/P6: A(2t+2)->b0   P7/P8: B(2t+3)->b1 + gate vmcnt(4)
#pragma unroll 1
    for (int t = 0; t < 15; ++t) {
        const int j1 = 2 * t + 1, j2 = 2 * t + 2, j3 = 2 * t + 3;
        PH(0, aU0, aU1, { RD_BURST(0); RDA(aU0,0,0); RDA(aU1,0,1); RDA(aV0,0,2); RDA(aV1,0,3); },
           STAGE_A(1, 0, j1), );
        PH(1, aV0, aV1, { RDA(aU0,0,4); RDA(aU1,0,5); }, STAGE_A(1, 1, j1), );
        PH(2, aU0, aU1, { RDA(aV0,0,6); RDA(aV1,0,7); }, STAGE_B(0, 0, j2), );
        PH(3, aV0, aV1, , STAGE_B(0, 1, j2), asm volatile("s_waitcnt vmcnt(4)" ::: "memory"));
        PH(0, aU0, aU1, { RD_BURST(1); RDA(aU0,1,0); RDA(aU1,1,1); RDA(aV0,1,2); RDA(aV1,1,3); },
           STAGE_A(0, 0, j2), );
        PH(1, aV0, aV1, { RDA(aU0,1,4); RDA(aU1,1,5); }, STAGE_A(0, 1, j2), );
        PH(2, aU0, aU1, { RDA(aV0,1,6); RDA(aV1,1,7); }, STAGE_B(1, 0, j3), );
        PH(3, aV0, aV1, , STAGE_B(1, 1, j3), asm volatile("s_waitcnt vmcnt(4)" ::: "memory"));
    }
    // tail: tiles 30 (buf0), 31 (buf1); A(31)->buf1 staged here, B(31) staged at t=14
    PH(0, aU0, aU1, { RD_BURST(0); RDA(aU0,0,0); RDA(aU1,0,1); RDA(aV0,0,2); RDA(aV1,0,3); },
       STAGE_A(1, 0, 31), );
    PH(1, aV0, aV1, { RDA(aU0,0,4); RDA(aU1,0,5); }, STAGE_A(1, 1, 31), );
    PH(2, aU0, aU1, { RDA(aV0,0,6); RDA(aV1,0,7); }, , );
    PH(3, aV0, aV1, , , asm volatile("s_waitcnt vmcnt(0)" ::: "memory"));
    PH(0, aU0, aU1, { RD_BURST(1); RDA(aU0,1,0); RDA(aU1,1,1); RDA(aV0,1,2); RDA(aV1,1,3); }, , );
    PH(1, aV0, aV1, { RDA(aU0,1,4); RDA(aU1,1,5); }, , );
    PH(2, aU0, aU1, { RDA(aV0,1,6); RDA(aV1,1,7); }, , );
    PH(3, aV0, aV1, , , );

    // epilogue: C[row][col] = acc + bias; row = m*16 + fq*4 + r, col = n*16 + fr (verified mapping)
#pragma unroll
    for (int n = 0; n < 4; ++n) {
        const int col = bcol * 256 + wc * 64 + n * 16 + fr;
        const float bv = bias[col];
#pragma unroll
        for (int m = 0; m < 8; ++m) {
            const int row0 = brow * 256 + wr * 128 + m * 16 + fq * 4;
#pragma unroll
            for (int r = 0; r < 4; ++r)
                C[(size_t)(row0 + r) * N + col] = acc[m][n][r] + bv;
        }
    }
#undef STAGE_A
#undef STAGE_B
#undef RDA
#undef RDB
#undef RD_BURST
#undef MM
#undef PH
}

extern "C" void kernel_launch(void* const* d_in, const int* in_sizes, int n_in,
                              void* d_out, int out_size, void* d_ws, size_t ws_size,
                              hipStream_t stream) {
    const float* x    = (const float*)d_in[0];
    const float* xh   = (const float*)d_in[1];
    const float* w    = (const float*)d_in[2];
    const float* bias = (const float*)d_in[3];
    const float* a0   = (const float*)d_in[4];
    const float* a1   = (const float*)d_in[5];
    const float* a2   = (const float*)d_in[6];
    const float* vals = (const float*)d_in[7];

    float* out  = (float*)d_out;
    float* outh = out + (size_t)4096 * 2048;

    char* ws = (char*)d_ws;
    unsigned short* xb  = (unsigned short*)(ws);                              // 16 MB
    unsigned short* xhb = (unsigned short*)(ws + (size_t)16 * 1024 * 1024);   // 16 MB
    unsigned short* wb  = (unsigned short*)(ws + (size_t)32 * 1024 * 1024);   //  8 MB
    unsigned short* hwb = (unsigned short*)(ws + (size_t)40 * 1024 * 1024);   //  8 MB

    prep_all<<<dim3(2048, 3), 256, 0, stream>>>(x, xh, w, a0, a1, a2, vals, xb, xhb, wb, hwb);

    dim3 grid(4096 / 256, 2048 / 256, 2);
    gemm256<<<grid, 512, 0, stream>>>(xb, xhb, wb, hwb, bias, out, outh);
}